// Round 4
// baseline (655.953 us; speedup 1.0000x reference)
//
#include <hip/hip_runtime.h>

// Quantum-LSTM forward. 512 blocks x 4 waves, 1 sample/block (verified
// constants from rounds 1-3). Round-4 changes:
//  1. Merged-pair gate coefficients K precomputed into an LDS table
//     [circuit][stage][parity-combo] (4.6 KB) -- in-loop each stage does two
//     explicit ds_read_b128 at loop-invariant per-lane offsets. Kills the
//     register-remat the compiler was doing (round-3: VGPR=128 < pinned set).
//  2. Shuffle masks expressible in <=2 exact DPP ops use VALU DPP
//     (quad_perm / row_mirror / row_half_mirror / row_ror:8) instead of the
//     DS pipe: masks 0x0F,0x07,0x02,0x05,0x0A + FWHT 1,2,3,4,8,12.
//  3. Embedding reverted to the round-2 readlane form (round-3's EF-LDS
//     publish added DS traffic and regressed).

namespace {

constexpr int BATCH  = 512;
constexpr int TSTEPS = 256;

typedef float v2f __attribute__((ext_vector_type(2)));

__device__ __forceinline__ v2f splat2(float s) { v2f r; r.x = s; r.y = s; return r; }
__device__ __forceinline__ v2f cswapneg(v2f v) { v2f r; r.x = -v.y; r.y = v.x; return r; }

__device__ __forceinline__ float sigf(float v) { return 1.0f / (1.0f + __expf(-v)); }
__device__ __forceinline__ float tanh_fast(float v) { return 1.0f - 2.0f / (1.0f + __expf(v + v)); }

__device__ __forceinline__ float rl(float v, int l) {
  return __int_as_float(__builtin_amdgcn_readlane(__float_as_int(v), l));
}

template<int CTRL>
__device__ __forceinline__ float dppmov(float v) {
  return __int_as_float(__builtin_amdgcn_mov_dpp(__float_as_int(v), CTRL, 0xF, 0xF, true));
}
// DPP ctrl: quad_perm[a,b,c,d] = a|b<<2|c<<4|d<<6 ; xor1=0xB1 xor2=0x4E xor3=0x1B
// row_mirror=0x140 (xorF), row_half_mirror=0x141 (xor7), row_ror:8=0x128 (xor8)

template<int M>
__device__ __forceinline__ float shx(float v, int lane4) {
  if constexpr      (M == 0x01) return dppmov<0xB1>(v);
  else if constexpr (M == 0x02) return dppmov<0x4E>(v);
  else if constexpr (M == 0x03) return dppmov<0x1B>(v);
  else if constexpr (M == 0x04) return dppmov<0x1B>(dppmov<0x141>(v));   // 7^3
  else if constexpr (M == 0x05) return dppmov<0x4E>(dppmov<0x141>(v));   // 7^2
  else if constexpr (M == 0x07) return dppmov<0x141>(v);
  else if constexpr (M == 0x08) return dppmov<0x128>(v);
  else if constexpr (M == 0x0A) return dppmov<0x4E>(dppmov<0x128>(v));   // 8^2
  else if constexpr (M == 0x0C) return dppmov<0x1B>(dppmov<0x140>(v));   // F^3
  else if constexpr (M == 0x0F) return dppmov<0x140>(v);
  else if constexpr (M < 32) {
    return __int_as_float(__builtin_amdgcn_ds_swizzle(__float_as_int(v), 0x1F | (M << 10)));
  } else {
    return __int_as_float(__builtin_amdgcn_ds_bpermute(lane4 ^ (M << 2), __float_as_int(v)));
  }
}

// u = K0 v + K1 v^M1 + K2 v^M2 + K3 v^(M1^M2)  (complex, packed)
template<int M1, int M2, int M12>
__device__ __forceinline__ void stagep(v2f& s, float4 kA, float4 kB, int lane4) {
  v2f v1, v2, v3;
  v1.x = shx<M1>(s.x, lane4);  v1.y = shx<M1>(s.y, lane4);
  v2.x = shx<M2>(s.x, lane4);  v2.y = shx<M2>(s.y, lane4);
  v3.x = shx<M12>(s.x, lane4); v3.y = shx<M12>(s.y, lane4);
  v2f u = splat2(kA.x) * s;
  u = __builtin_elementwise_fma(splat2(kA.y), cswapneg(s),  u);
  u = __builtin_elementwise_fma(splat2(kA.z), v1,           u);
  u = __builtin_elementwise_fma(splat2(kA.w), cswapneg(v1), u);
  u = __builtin_elementwise_fma(splat2(kB.x), v2,           u);
  u = __builtin_elementwise_fma(splat2(kB.y), cswapneg(v2), u);
  u = __builtin_elementwise_fma(splat2(kB.z), v3,           u);
  u = __builtin_elementwise_fma(splat2(kB.w), cswapneg(v3), u);
  s = u;
}

__device__ __forceinline__ void gate_chain(v2f& s, const float4* __restrict__ Kt,
                                           const int (&off)[6], int lane4) {
  { float4 kA = Kt[off[0]], kB = Kt[off[0]+1]; stagep<0x0F,0x1E,0x11>(s, kA, kB, lane4); }
  { float4 kA = Kt[off[1]], kB = Kt[off[1]+1]; stagep<0x3C,0x3B,0x07>(s, kA, kB, lane4); }
  { float4 kA = Kt[off[2]], kB = Kt[off[2]+1]; stagep<0x3F,0x3D,0x02>(s, kA, kB, lane4); }
  { float4 kA = Kt[off[3]], kB = Kt[off[3]+1]; stagep<0x16,0x26,0x30>(s, kA, kB, lane4); }
  { float4 kA = Kt[off[4]], kB = Kt[off[4]+1]; stagep<0x05,0x28,0x2D>(s, kA, kB, lane4); }
  { float4 kA = Kt[off[5]], kB = Kt[off[5]+1]; stagep<0x14,0x0A,0x1E>(s, kA, kB, lane4); }
}

// merged FWHT + final gather
__device__ __forceinline__ float expvals(v2f s, const float (&fs)[9],
                                         int lane4, int gaddr) {
  float p  = fmaf(s.x, s.x, s.y * s.y);
  float pa = shx<1>(p, lane4), pb = shx<2>(p, lane4), pc = shx<3>(p, lane4);
  p = fmaf(fs[0], p, fmaf(fs[1], pa, fmaf(fs[2], pb, pc)));
  pa = shx<4>(p, lane4); pb = shx<8>(p, lane4); pc = shx<12>(p, lane4);
  p = fmaf(fs[3], p, fmaf(fs[4], pa, fmaf(fs[5], pb, pc)));
  pa = shx<16>(p, lane4); pb = shx<32>(p, lane4); pc = shx<48>(p, lane4);
  p = fmaf(fs[6], p, fmaf(fs[7], pa, fmaf(fs[8], pb, pc)));
  return __int_as_float(__builtin_amdgcn_ds_bpermute(gaddr, __float_as_int(p)));
}

// half-angle products for wire value Xv: A=c1c2 B=c1s2 C=s1c2 D=s1s2
__device__ __forceinline__ void trig(float Xv, float& A_, float& B_, float& C_, float& D_) {
  float tq   = Xv * Xv;
  float cth1 = rsqrtf(1.f + tq);
  float sth1 = Xv * cth1;
  float u1   = 1.f + cth1, r1 = rsqrtf(u1 + u1);
  float c1   = u1 * r1,    s1 = sth1 * r1;
  float tq2  = tq * tq;
  float cth2 = rsqrtf(1.f + tq2);
  float sth2 = tq * cth2;
  float u2   = 1.f + cth2, r2 = rsqrtf(u2 + u2);
  float c2   = u2 * r2,    s2 = sth2 * r2;
  A_ = c1 * c2; B_ = c1 * s2; C_ = s1 * c2; D_ = s1 * s2;
}

// product-state embedding via readlane broadcast (round-2 form)
__device__ __forceinline__ v2f embed_rl(float A_, float B_, float C_, float D_, int lane) {
  float ar, ai;
  {
    float Aj = rl(A_,0), Bj = rl(B_,0), Cj = rl(C_,0), Dj = rl(D_,0);
    bool bj = lane & 1;
    ar = bj ? Cj : Aj;
    ai = bj ? Dj : -Bj;
  }
#pragma unroll
  for (int jj = 1; jj < 6; ++jj) {
    float Aj = rl(A_,jj), Bj = rl(B_,jj), Cj = rl(C_,jj), Dj = rl(D_,jj);
    bool bj = (lane >> jj) & 1;
    float fr = bj ? Cj : Aj;
    float fi = bj ? Dj : -Bj;
    float nr = ar * fr - ai * fi;
    ai = fmaf(ar, fi, ai * fr);
    ar = nr;
  }
  v2f s; s.x = ar; s.y = ai; return s;
}

#define PACK_IDX ((0x2AULL)|(0x15ULL<<6)|(0x01ULL<<12)|(0x35ULL<<18)|(0x3AULL<<24)|(0x3DULL<<30))

} // namespace

__global__ __launch_bounds__(256, 2)
void qlstm_kernel(const float* __restrict__ x, const float* __restrict__ phi,
                  const float* __restrict__ Wc, const float* __restrict__ bc,
                  float* __restrict__ out)
{
  __shared__ float4 fG[144];      // 6 circuits x 12 gates x {G00G01, G10G11}
  __shared__ float4 Kt[288];      // [circuit][stage][combo] x {kA,kB}
  __shared__ float4 gates4[6];    // per-wire (f,i,C,o), sigmoided
  __shared__ float  h_s[6];

  const int tid   = threadIdx.x;
  const int wave  = tid >> 6;
  const int lane  = tid & 63;
  const int lane4 = lane << 2;
  const int b     = blockIdx.x;

  // ---- one-time: fused gate matrices G = RZ*RY*RX per (circuit,layer,wire) ----
  if (tid < 72) {
    int g = tid / 12, rem = tid % 12, l = rem / 6, i = rem % 6;
    const float* w = phi + g*36 + l*18 + i*3;
    float sa, ca, sb, cb, sc, cc;
    sincosf(0.5f * w[0], &sa, &ca);
    sincosf(0.5f * w[1], &sb, &cb);
    sincosf(0.5f * w[2], &sc, &cc);
    float m00r =  cb*ca, m00i =  sb*sa;
    float m01r = -sb*ca, m01i = -cb*sa;
    float m10r =  sb*ca, m10i = -cb*sa;
    float m11r =  cb*ca, m11i = -sb*sa;
    float4 A, Bv;
    A.x  = m00r*cc + m00i*sc;  A.y  = m00i*cc - m00r*sc;
    A.z  = m01r*cc + m01i*sc;  A.w  = m01i*cc - m01r*sc;
    Bv.x = m10r*cc - m10i*sc;  Bv.y = m10i*cc + m10r*sc;
    Bv.z = m11r*cc - m11i*sc;  Bv.w = m11i*cc + m11r*sc;
    fG[2*tid] = A; fG[2*tid+1] = Bv;
  }
  if (tid < 6) h_s[tid] = 0.f;
  __syncthreads();

  // ---- one-time: merged-pair K table, all 4 parity combos ----
  if (tid < 144) {
    int c = tid / 24, rem = tid % 24, s = rem / 4, combo = rem & 3;
    int p1 = combo & 1, p2 = combo >> 1;
    int l = s / 3, i0 = (s % 3) * 2;
    float4 ga1 = fG[(c*12 + l*6 + i0    )*2], gb1 = fG[(c*12 + l*6 + i0    )*2+1];
    float4 ga2 = fG[(c*12 + l*6 + i0 + 1)*2], gb2 = fG[(c*12 + l*6 + i0 + 1)*2+1];
    float arr = p1 ? gb1.z : ga1.x, ari = p1 ? gb1.w : ga1.y;
    float brr = p1 ? gb1.x : ga1.z, bri = p1 ? gb1.y : ga1.w;
    float crr = p2 ? gb2.z : ga2.x, cri = p2 ? gb2.w : ga2.y;
    float drr = p2 ? gb2.x : ga2.z, dri = p2 ? gb2.y : ga2.w;
    Kt[tid*2]   = make_float4(crr*arr - cri*ari, crr*ari + cri*arr,
                              crr*brr - cri*bri, crr*bri + cri*brr);
    Kt[tid*2+1] = make_float4(drr*arr - dri*ari, drr*ari + dri*arr,
                              drr*brr - dri*bri, drr*bri + dri*brr);
  }
  __syncthreads();

  // ---- per-wave/lane loop-invariants ----
  const int j = (lane < 6) ? lane : 0;           // owned wire
  float Wr[14];
#pragma unroll
  for (int k = 0; k < 14; ++k) Wr[k] = Wc[j*14 + k];
  const float bcj = bc[j];

  float sgn[6];
#pragma unroll
  for (int k = 0; k < 6; ++k) sgn[k] = ((lane >> k) & 1) ? -1.f : 1.f;
  float fs[9] = { sgn[0]*sgn[1], sgn[1], sgn[0],
                  sgn[2]*sgn[3], sgn[3], sgn[2],
                  sgn[4]*sgn[5], sgn[5], sgn[4] };

  int sh    = (lane < 6) ? (6 * lane) : 0;
  int gaddr = (int)((PACK_IDX >> sh) & 63ULL) << 2;

  // per-lane parity bits (gate-ordered) -> per-stage K-table offsets
  constexpr unsigned BM[2][6] = {
    {0x18,0x30,0x39,0x0C,0x26,0x33},
    {0x2A,0x15,0x01,0x35,0x3A,0x3D}};
  unsigned bm = 0;
#pragma unroll
  for (int l = 0; l < 2; ++l)
#pragma unroll
    for (int i = 0; i < 6; ++i)
      bm |= (unsigned)(__popc(lane & (int)BM[l][i]) & 1) << (l*6+i);

  int off1[6], off2[6];
  const int c2id = 4 + (wave & 1);
#pragma unroll
  for (int s = 0; s < 6; ++s) {
    int cb = (int)((bm >> (2*s)) & 3u);
    off1[s] = ((wave*6 + s)*4 + cb)*2;
    off2[s] = ((c2id*6 + s)*4 + cb)*2;
  }

  float c_sc  = 0.f;   // lane i (<6) of waves 0,1 owns c_i
  float hlast = 0.f;

  const float* xbase = x + (size_t)b * TSTEPS * 8;
  float4 xa = *(const float4*)(xbase);
  float4 xb = *(const float4*)(xbase + 4);

  for (int t = 0; t < TSTEPS; ++t) {
    // ---- phase 1: X_j in lane j, readlane-broadcast embed, circuit f/i/C/o ----
    float hv0 = h_s[0], hv1 = h_s[1], hv2 = h_s[2];
    float hv3 = h_s[3], hv4 = h_s[4], hv5 = h_s[5];
    float acc = bcj;
    acc = fmaf(xa.x, Wr[0],  acc); acc = fmaf(xa.y, Wr[1],  acc);
    acc = fmaf(xa.z, Wr[2],  acc); acc = fmaf(xa.w, Wr[3],  acc);
    acc = fmaf(xb.x, Wr[4],  acc); acc = fmaf(xb.y, Wr[5],  acc);
    acc = fmaf(xb.z, Wr[6],  acc); acc = fmaf(xb.w, Wr[7],  acc);
    acc = fmaf(hv0,  Wr[8],  acc); acc = fmaf(hv1,  Wr[9],  acc);
    acc = fmaf(hv2,  Wr[10], acc); acc = fmaf(hv3,  Wr[11], acc);
    acc = fmaf(hv4,  Wr[12], acc); acc = fmaf(hv5,  Wr[13], acc);
    float Xj = 1.f - 2.f / (1.f + __expf(acc));

    // prefetch next x (overlaps the circuit)
    int tn = (t + 1 < TSTEPS) ? (t + 1) : t;
    float4 xa_n = *(const float4*)(xbase + (size_t)tn * 8);
    float4 xb_n = *(const float4*)(xbase + (size_t)tn * 8 + 4);

    float A_, B_, C_, D_;
    trig(Xj, A_, B_, C_, D_);
    v2f s = embed_rl(A_, B_, C_, D_, lane);
    gate_chain(s, Kt, off1, lane4);
    float Wv  = expvals(s, fs, lane4, gaddr);
    float sgv = sigf(Wv);
    if (lane < 6) ((float*)&gates4[lane])[wave] = sgv;
    __syncthreads();

    // ---- phase 2: cell update + circuits h (wave0), y (wave1) ----
    if (wave < 2) {
      float4 g4 = gates4[j];                       // (f,i,C,o) for wire j
      float cn  = fmaf(g4.x, c_sc, g4.y * g4.z);
      c_sc = cn;
      float resc = g4.w * tanh_fast(cn);
      float A2, B2, C2, D2;
      trig(resc, A2, B2, C2, D2);
      v2f s2 = embed_rl(A2, B2, C2, D2, lane);
      gate_chain(s2, Kt, off2, lane4);
      float Wv2 = expvals(s2, fs, lane4, gaddr);
      if (wave == 0) {
        if (lane < 6) h_s[lane] = Wv2;
        hlast = Wv2;
      } else if (lane < 6) {
        out[((size_t)b * TSTEPS + t) * 6 + lane] = Wv2;
      }
    }
    xa = xa_n; xb = xb_n;
    __syncthreads();
  }

  // ---- final c, h ----
  if (wave == 0 && lane < 6) {
    size_t cbase = (size_t)BATCH * TSTEPS * 6;
    out[cbase + (size_t)b * 6 + lane] = c_sc;
    out[cbase + (size_t)BATCH * 6 + (size_t)b * 6 + lane] = hlast;
  }
}

extern "C" void kernel_launch(void* const* d_in, const int* in_sizes, int n_in,
                              void* d_out, int out_size, void* d_ws, size_t ws_size,
                              hipStream_t stream) {
  const float* x   = (const float*)d_in[0];
  const float* phi = (const float*)d_in[1];
  const float* Wc  = (const float*)d_in[2];
  const float* bc  = (const float*)d_in[3];
  float* out = (float*)d_out;
  (void)in_sizes; (void)n_in; (void)out_size; (void)d_ws; (void)ws_size;
  hipLaunchKernelGGL(qlstm_kernel, dim3(BATCH), dim3(256), 0, stream,
                     x, phi, Wc, bc, out);
}

// Round 5
// 622.586 us; speedup vs baseline: 1.0536x; 1.0536x over previous
//
#include <hip/hip_runtime.h>

// Quantum-LSTM forward. 512 blocks x 4 waves, 1 sample/block (structure and
// GF(2)/shuffle constants verified rounds 1-4). Round-5 changes:
//  1. UN-merged 12-gate chain with WAVE-UNIFORM coefficients: G is SU(2), so
//     the per-lane parity select row0/row1 == conjugate-and-negate, applied
//     as one v_xor on the sign bit of two coefficient components. Kills all
//     per-lane K machinery (R2 remat / R3 pressure / R4 LDS reads).
//     DS shuffle ops per circuit: 36 -> 18 (plus 3 gates on verified DPP).
//  2. Coefficients (12 float4/circuit) loaded once from LDS, pinned in VGPRs
//     (waves_per_eu(2,2): 256-VGPR budget, R3 proved pins hold residency).
//  3. FWHT masks {1,2,3,4,8,12} on verified DPP; {16,32,48} stay DS.

namespace {

constexpr int BATCH  = 512;
constexpr int TSTEPS = 256;

typedef float v2f __attribute__((ext_vector_type(2)));

__device__ __forceinline__ v2f splat2(float s) { v2f r; r.x = s; r.y = s; return r; }
__device__ __forceinline__ v2f cswapneg(v2f v) { v2f r; r.x = -v.y; r.y = v.x; return r; }

__device__ __forceinline__ float sigf(float v) { return 1.0f / (1.0f + __expf(-v)); }
__device__ __forceinline__ float tanh_fast(float v) { return 1.0f - 2.0f / (1.0f + __expf(v + v)); }

__device__ __forceinline__ float rl(float v, int l) {
  return __int_as_float(__builtin_amdgcn_readlane(__float_as_int(v), l));
}

template<int CTRL>
__device__ __forceinline__ float dppmov(float v) {
  return __int_as_float(__builtin_amdgcn_mov_dpp(__float_as_int(v), CTRL, 0xF, 0xF, true));
}
// Verified (R4): quad_perm xor1=0xB1 xor2=0x4E xor3=0x1B; row_half_mirror=0x141
// (xor7), row_ror:8=0x128 (xor8), row_mirror=0x140 (xorF); composites 4,5,A,C.

template<int M>
__device__ __forceinline__ float shx(float v, int lane4) {
  if constexpr      (M == 0x01) return dppmov<0xB1>(v);
  else if constexpr (M == 0x02) return dppmov<0x4E>(v);
  else if constexpr (M == 0x03) return dppmov<0x1B>(v);
  else if constexpr (M == 0x04) return dppmov<0x1B>(dppmov<0x141>(v));
  else if constexpr (M == 0x05) return dppmov<0x4E>(dppmov<0x141>(v));
  else if constexpr (M == 0x07) return dppmov<0x141>(v);
  else if constexpr (M == 0x08) return dppmov<0x128>(v);
  else if constexpr (M == 0x0A) return dppmov<0x4E>(dppmov<0x128>(v));
  else if constexpr (M == 0x0C) return dppmov<0x1B>(dppmov<0x140>(v));
  else if constexpr (M == 0x0F) return dppmov<0x140>(v);
  else if constexpr (M < 32) {
    return __int_as_float(__builtin_amdgcn_ds_swizzle(__float_as_int(v), 0x1F | (M << 10)));
  } else {
    return __int_as_float(__builtin_amdgcn_ds_bpermute(lane4 ^ (M << 2), __float_as_int(v)));
  }
}

// one gate: uniform coeffs A=(G00r,G00i,G01r,G01i), per-lane sign mask pm
// (0 or 0x80000000). Row select == conj-neg: coeffs (A.x, s*A.y), (s*A.z, A.w).
template<int M>
__device__ __forceinline__ void gate1(v2f& s, float4 A, int pm, int lane4) {
  v2f v; v.x = shx<M>(s.x, lane4); v.y = shx<M>(s.y, lane4);
  float sai = __int_as_float(__float_as_int(A.y) ^ pm);
  float sbr = __int_as_float(__float_as_int(A.z) ^ pm);
  v2f u = splat2(A.x) * s;
  u = __builtin_elementwise_fma(splat2(sai), cswapneg(s), u);
  u = __builtin_elementwise_fma(splat2(sbr), v,           u);
  u = __builtin_elementwise_fma(splat2(A.w), cswapneg(v), u);
  s = u;
}

__device__ __forceinline__ void gate_chain(v2f& s, const float4 (&CA)[12],
                                           const int (&pm)[12], int lane4) {
  gate1<0x0F>(s, CA[0],  pm[0],  lane4);
  gate1<0x1E>(s, CA[1],  pm[1],  lane4);
  gate1<0x3C>(s, CA[2],  pm[2],  lane4);
  gate1<0x3B>(s, CA[3],  pm[3],  lane4);
  gate1<0x3F>(s, CA[4],  pm[4],  lane4);
  gate1<0x3D>(s, CA[5],  pm[5],  lane4);
  gate1<0x16>(s, CA[6],  pm[6],  lane4);
  gate1<0x26>(s, CA[7],  pm[7],  lane4);
  gate1<0x05>(s, CA[8],  pm[8],  lane4);
  gate1<0x28>(s, CA[9],  pm[9],  lane4);
  gate1<0x14>(s, CA[10], pm[10], lane4);
  gate1<0x0A>(s, CA[11], pm[11], lane4);
}

// merged FWHT + final gather
__device__ __forceinline__ float expvals(v2f s, const float (&fs)[9],
                                         int lane4, int gaddr) {
  float p  = fmaf(s.x, s.x, s.y * s.y);
  float pa = shx<1>(p, lane4), pb = shx<2>(p, lane4), pc = shx<3>(p, lane4);
  p = fmaf(fs[0], p, fmaf(fs[1], pa, fmaf(fs[2], pb, pc)));
  pa = shx<4>(p, lane4); pb = shx<8>(p, lane4); pc = shx<12>(p, lane4);
  p = fmaf(fs[3], p, fmaf(fs[4], pa, fmaf(fs[5], pb, pc)));
  pa = shx<16>(p, lane4); pb = shx<32>(p, lane4); pc = shx<48>(p, lane4);
  p = fmaf(fs[6], p, fmaf(fs[7], pa, fmaf(fs[8], pb, pc)));
  return __int_as_float(__builtin_amdgcn_ds_bpermute(gaddr, __float_as_int(p)));
}

// half-angle products for wire value Xv: A=c1c2 B=c1s2 C=s1c2 D=s1s2
__device__ __forceinline__ void trig(float Xv, float& A_, float& B_, float& C_, float& D_) {
  float tq   = Xv * Xv;
  float cth1 = rsqrtf(1.f + tq);
  float sth1 = Xv * cth1;
  float u1   = 1.f + cth1, r1 = rsqrtf(u1 + u1);
  float c1   = u1 * r1,    s1 = sth1 * r1;
  float tq2  = tq * tq;
  float cth2 = rsqrtf(1.f + tq2);
  float sth2 = tq * cth2;
  float u2   = 1.f + cth2, r2 = rsqrtf(u2 + u2);
  float c2   = u2 * r2,    s2 = sth2 * r2;
  A_ = c1 * c2; B_ = c1 * s2; C_ = s1 * c2; D_ = s1 * s2;
}

// product-state embedding via readlane broadcast (verified R2 form)
__device__ __forceinline__ v2f embed_rl(float A_, float B_, float C_, float D_, int lane) {
  float ar, ai;
  {
    float Aj = rl(A_,0), Bj = rl(B_,0), Cj = rl(C_,0), Dj = rl(D_,0);
    bool bj = lane & 1;
    ar = bj ? Cj : Aj;
    ai = bj ? Dj : -Bj;
  }
#pragma unroll
  for (int jj = 1; jj < 6; ++jj) {
    float Aj = rl(A_,jj), Bj = rl(B_,jj), Cj = rl(C_,jj), Dj = rl(D_,jj);
    bool bj = (lane >> jj) & 1;
    float fr = bj ? Cj : Aj;
    float fi = bj ? Dj : -Bj;
    float nr = ar * fr - ai * fi;
    ai = fmaf(ar, fi, ai * fr);
    ar = nr;
  }
  v2f s; s.x = ar; s.y = ai; return s;
}

#define PACK_IDX ((0x2AULL)|(0x15ULL<<6)|(0x01ULL<<12)|(0x35ULL<<18)|(0x3AULL<<24)|(0x3DULL<<30))
#define PIN4(v) asm volatile("" : "+v"((v).x), "+v"((v).y), "+v"((v).z), "+v"((v).w))

} // namespace

__global__ __attribute__((amdgpu_flat_work_group_size(256, 256)))
           __attribute__((amdgpu_waves_per_eu(2, 2)))
void qlstm_kernel(const float* __restrict__ x, const float* __restrict__ phi,
                  const float* __restrict__ Wc, const float* __restrict__ bc,
                  float* __restrict__ out)
{
  __shared__ float4 fG[72];        // 6 circuits x 12 gates, row0 only (G00,G01)
  __shared__ float4 gates4[6];     // per-wire (f,i,C,o), sigmoided
  __shared__ __align__(16) float h_s[8];

  const int tid   = threadIdx.x;
  const int wave  = tid >> 6;
  const int lane  = tid & 63;
  const int lane4 = lane << 2;
  const int b     = blockIdx.x;

  // ---- one-time: fused gate row0 per (circuit,layer,wire) ----
  if (tid < 72) {
    int g = tid / 12, rem = tid % 12, l = rem / 6, i = rem % 6;
    const float* w = phi + g*36 + l*18 + i*3;
    float sa, ca, sb, cb, sc, cc;
    sincosf(0.5f * w[0], &sa, &ca);
    sincosf(0.5f * w[1], &sb, &cb);
    sincosf(0.5f * w[2], &sc, &cc);
    float m00r =  cb*ca, m00i =  sb*sa;
    float m01r = -sb*ca, m01i = -cb*sa;
    float4 A;
    A.x = m00r*cc + m00i*sc;  A.y = m00i*cc - m00r*sc;
    A.z = m01r*cc + m01i*sc;  A.w = m01i*cc - m01r*sc;
    fG[tid] = A;
  }
  if (tid < 8) h_s[tid] = 0.f;
  __syncthreads();

  // ---- per-wave/lane loop-invariants ----
  const int j = (lane < 6) ? lane : 0;           // owned wire
  float Wr[14];
#pragma unroll
  for (int k = 0; k < 14; ++k) Wr[k] = Wc[j*14 + k];
  const float bcj = bc[j];

  float sgn[6];
#pragma unroll
  for (int k = 0; k < 6; ++k) sgn[k] = ((lane >> k) & 1) ? -1.f : 1.f;
  float fs[9] = { sgn[0]*sgn[1], sgn[1], sgn[0],
                  sgn[2]*sgn[3], sgn[3], sgn[2],
                  sgn[4]*sgn[5], sgn[5], sgn[4] };

  int sh    = (lane < 6) ? (6 * lane) : 0;
  int gaddr = (int)((PACK_IDX >> sh) & 63ULL) << 2;

  // per-lane sign masks (gate order), circuit-independent
  constexpr unsigned BM[2][6] = {
    {0x18,0x30,0x39,0x0C,0x26,0x33},
    {0x2A,0x15,0x01,0x35,0x3A,0x3D}};
  int pm[12];
#pragma unroll
  for (int l = 0; l < 2; ++l)
#pragma unroll
    for (int i = 0; i < 6; ++i)
      pm[l*6+i] = (__popc(lane & (int)BM[l][i]) & 1) << 31;
#pragma unroll
  for (int g = 0; g < 12; ++g) asm volatile("" : "+v"(pm[g]));

  // uniform coefficient sets: phase-1 circuit (wave) and phase-2 (4+wave&1)
  float4 CA1[12], CA2[12];
#pragma unroll
  for (int i = 0; i < 12; ++i) {
    CA1[i] = fG[wave * 12 + i];
    CA2[i] = fG[(4 + (wave & 1)) * 12 + i];
  }
#pragma unroll
  for (int i = 0; i < 12; ++i) { PIN4(CA1[i]); PIN4(CA2[i]); }

  float c_sc  = 0.f;   // lane i (<6) of waves 0,1 owns c_i
  float hlast = 0.f;

  const float* xbase = x + (size_t)b * TSTEPS * 8;
  float4 xa = *(const float4*)(xbase);
  float4 xb = *(const float4*)(xbase + 4);

  for (int t = 0; t < TSTEPS; ++t) {
    // ---- phase 1: X_j in lane j, embed, circuit (f,i,C,o per wave) ----
    float4 h4 = *(const float4*)&h_s[0];
    float2 h2 = *(const float2*)&h_s[4];
    float acc = bcj;
    acc = fmaf(xa.x, Wr[0],  acc); acc = fmaf(xa.y, Wr[1],  acc);
    acc = fmaf(xa.z, Wr[2],  acc); acc = fmaf(xa.w, Wr[3],  acc);
    acc = fmaf(xb.x, Wr[4],  acc); acc = fmaf(xb.y, Wr[5],  acc);
    acc = fmaf(xb.z, Wr[6],  acc); acc = fmaf(xb.w, Wr[7],  acc);
    acc = fmaf(h4.x, Wr[8],  acc); acc = fmaf(h4.y, Wr[9],  acc);
    acc = fmaf(h4.z, Wr[10], acc); acc = fmaf(h4.w, Wr[11], acc);
    acc = fmaf(h2.x, Wr[12], acc); acc = fmaf(h2.y, Wr[13], acc);
    float Xj = 1.f - 2.f / (1.f + __expf(acc));

    // prefetch next x (overlaps the circuit)
    int tn = (t + 1 < TSTEPS) ? (t + 1) : t;
    float4 xa_n = *(const float4*)(xbase + (size_t)tn * 8);
    float4 xb_n = *(const float4*)(xbase + (size_t)tn * 8 + 4);

    float A_, B_, C_, D_;
    trig(Xj, A_, B_, C_, D_);
    v2f s = embed_rl(A_, B_, C_, D_, lane);
    gate_chain(s, CA1, pm, lane4);
    float Wv  = expvals(s, fs, lane4, gaddr);
    float sgv = sigf(Wv);
    if (lane < 6) ((float*)&gates4[lane])[wave] = sgv;
    __syncthreads();

    // ---- phase 2: cell update + circuits h (wave0), y (wave1) ----
    if (wave < 2) {
      float4 g4 = gates4[j];                       // (f,i,C,o) for wire j
      float cn  = fmaf(g4.x, c_sc, g4.y * g4.z);
      c_sc = cn;
      float resc = g4.w * tanh_fast(cn);
      float A2, B2, C2, D2;
      trig(resc, A2, B2, C2, D2);
      v2f s2 = embed_rl(A2, B2, C2, D2, lane);
      gate_chain(s2, CA2, pm, lane4);
      float Wv2 = expvals(s2, fs, lane4, gaddr);
      if (wave == 0) {
        if (lane < 6) h_s[lane] = Wv2;
        hlast = Wv2;
      } else if (lane < 6) {
        out[((size_t)b * TSTEPS + t) * 6 + lane] = Wv2;
      }
    }
    xa = xa_n; xb = xb_n;
    __syncthreads();
  }

  // ---- final c, h ----
  if (wave == 0 && lane < 6) {
    size_t cbase = (size_t)BATCH * TSTEPS * 6;
    out[cbase + (size_t)b * 6 + lane] = c_sc;
    out[cbase + (size_t)BATCH * 6 + (size_t)b * 6 + lane] = hlast;
  }
}

extern "C" void kernel_launch(void* const* d_in, const int* in_sizes, int n_in,
                              void* d_out, int out_size, void* d_ws, size_t ws_size,
                              hipStream_t stream) {
  const float* x   = (const float*)d_in[0];
  const float* phi = (const float*)d_in[1];
  const float* Wc  = (const float*)d_in[2];
  const float* bc  = (const float*)d_in[3];
  float* out = (float*)d_out;
  (void)in_sizes; (void)n_in; (void)out_size; (void)d_ws; (void)ws_size;
  hipLaunchKernelGGL(qlstm_kernel, dim3(BATCH), dim3(256), 0, stream,
                     x, phi, Wc, bc, out);
}